// Round 13
// baseline (246.982 us; speedup 1.0000x reference)
//
#include <hip/hip_runtime.h>

#define B_    4
#define T_    2048
#define H_    1024
#define S_    512
#define HALF_ 256
#define LOC_  1024
#define BT_   8192          // B*T rows
#define N1_   6400          // proj cols: 8*512 + 256 + 1024 + 1024 (up/gate interleaved)
#define K1_   1024
#define N2_   1024
#define K2_   2048
#define NCH_  32            // scan chunks
#define LC_   64            // chunk length (T_/NCH_)

typedef __attribute__((ext_vector_type(8))) short  bf16x8;
typedef __attribute__((ext_vector_type(4))) float  f32x4;
typedef __attribute__((ext_vector_type(4))) unsigned short u16x4;

__device__ __forceinline__ float b2f(unsigned short u) {
    union { unsigned i; float f; } v; v.i = ((unsigned)u) << 16; return v.f;
}
__device__ __forceinline__ unsigned short f2b(float f) {
    union { float f; unsigned i; } v; v.f = f;
    unsigned r = v.i + 0x7fffu + ((v.i >> 16) & 1u);
    return (unsigned short)(r >> 16);
}
__device__ __forceinline__ float rcp_(float x) { return __builtin_amdgcn_rcpf(x); }
__device__ __forceinline__ float sigm_(float v) { return rcp_(1.f + __expf(-v)); }
__device__ __forceinline__ float silu_(float v) { return v * rcp_(1.f + __expf(-v)); }
__device__ __forceinline__ float tanh_(float v) { return 1.f - 2.f * rcp_(1.f + __expf(2.f * v)); }

__device__ __forceinline__ void gload16(const void* g, void* l) {
    __builtin_amdgcn_global_load_lds(
        (const __attribute__((address_space(1))) void*)g,
        (__attribute__((address_space(3))) void*)l,
        16, 0, 0);
}

#define SB0    __builtin_amdgcn_sched_barrier(0)
#define BARR   __builtin_amdgcn_s_barrier()
#define WAITV4 asm volatile("s_waitcnt vmcnt(4)" ::: "memory")
#define WAITV3 asm volatile("s_waitcnt vmcnt(3)" ::: "memory")
#define WAITV0 asm volatile("s_waitcnt vmcnt(0)" ::: "memory")

// ---------------------------------------------------------------- fused pack_x + mix
__global__ void prep_x(const float* __restrict__ x, const float* __restrict__ Wm,
                       unsigned short* __restrict__ xb, float4* __restrict__ mw) {
    const int row  = blockIdx.x * 4 + (threadIdx.x >> 6);
    const int lane = threadIdx.x & 63;
    const float4* xr = (const float4*)(x + (size_t)row * H_);
    u16x4* xbr = (u16x4*)(xb + (size_t)row * H_);
    float s0 = 0.f, s1 = 0.f, s2 = 0.f;
#pragma unroll
    for (int p = 0; p < 4; p++) {
        const int k4 = p * 64 + lane;
        float4 v = xr[k4];
        u16x4 u;
        u.x = f2b(v.x); u.y = f2b(v.y); u.z = f2b(v.z); u.w = f2b(v.w);
        xbr[k4] = u;
        const int k3 = k4 * 12;
        s0 += v.x * Wm[k3 + 0] + v.y * Wm[k3 + 3] + v.z * Wm[k3 + 6] + v.w * Wm[k3 + 9];
        s1 += v.x * Wm[k3 + 1] + v.y * Wm[k3 + 4] + v.z * Wm[k3 + 7] + v.w * Wm[k3 + 10];
        s2 += v.x * Wm[k3 + 2] + v.y * Wm[k3 + 5] + v.z * Wm[k3 + 8] + v.w * Wm[k3 + 11];
    }
#pragma unroll
    for (int off = 32; off; off >>= 1) {
        s0 += __shfl_down(s0, off);
        s1 += __shfl_down(s1, off);
        s2 += __shfl_down(s2, off);
    }
    if (lane == 0) {
        float m = fmaxf(s0, fmaxf(s1, s2));
        float e0 = __expf(s0 - m), e1 = __expf(s1 - m), e2 = __expf(s2 - m);
        float inv = 1.f / (e0 + e1 + e2);
        mw[row] = (float4){ e0 * inv, e1 * inv, e2 * inv, 0.f };
    }
}

// ------------------------------------------------- transpose-pack weights to [n][k] bf16
// ilv: 0 = plain; 1 = up-half of 32-col superblock; 2 = gate-half.
struct TOp { const float* src; int Kw; int Nw; int n_ofs; int k_ofs; int which; int ilv; };
struct TOps { TOp v[14]; };

__global__ void pack_w_kernel(TOps ops, unsigned short* __restrict__ w1, unsigned short* __restrict__ w2) {
    TOp op = ops.v[blockIdx.z];
    int kt = blockIdx.x * 32, nt = blockIdx.y * 32;
    if (kt >= op.Kw || nt >= op.Nw) return;
    __shared__ float tile[32][33];
    int tx = threadIdx.x & 31, ty = threadIdx.x >> 5;   // 32 x 8
#pragma unroll
    for (int r = 0; r < 4; r++) {
        int k = kt + ty + r * 8;
        tile[ty + r * 8][tx] = op.src[(size_t)k * op.Nw + nt + tx];
    }
    __syncthreads();
    unsigned short* dst = op.which ? w2 : w1;
    int stride = op.which ? K2_ : K1_;
#pragma unroll
    for (int r = 0; r < 4; r++) {
        int n = nt + ty + r * 8;
        int dcol;
        if (op.ilv)
            dcol = op.n_ofs + ((n >> 4) << 5) + ((op.ilv == 2) ? 16 : 0) + (n & 15);
        else
            dcol = op.n_ofs + n;
        dst[(size_t)dcol * stride + op.k_ofs + kt + tx] = f2b(tile[tx][ty + r * 8]);
    }
}

// ---------------------------------------------------------------- GEMM1 (R12-proven)
// Counted-vmcnt double-buffer, XCD-aware bijective swizzle, wave-private epilogue.
// Regions: 0=tanh 1=sigm 2=silu 3=id 4=sigm(-v) 5=som(cos/sin)
//          6=fused local branch: G = mw.z * up * silu(gate)  (up/gate interleaved cols)
#define STAGE(kt_, dA, dB) {          \
    gload16(aP0 + (kt_), (dA));       \
    gload16(aP1 + (kt_), (dA) + 512); \
    gload16(bP0 + (kt_), (dB));       \
    gload16(bP1 + (kt_), (dB) + 512); }

#define COMPUTE(sAr, sBr) {                                                            \
    bf16x8 af[4], bfv[4];                                                              \
    _Pragma("unroll")                                                                  \
    for (int m_ = 0; m_ < 4; m_++)                                                     \
        af[m_] = *(const bf16x8*)((sAr) + (wm + m_ * 16 + fr) * 32 + rsl);             \
    _Pragma("unroll")                                                                  \
    for (int n_ = 0; n_ < 4; n_++)                                                     \
        bfv[n_] = *(const bf16x8*)((sBr) + (wn + n_ * 16 + fr) * 32 + rsl);            \
    _Pragma("unroll")                                                                  \
    for (int m_ = 0; m_ < 4; m_++)                                                     \
        _Pragma("unroll")                                                              \
        for (int n_ = 0; n_ < 4; n_++)                                                 \
            acc[m_][n_] = __builtin_amdgcn_mfma_f32_16x16x32_bf16(af[m_], bfv[n_], acc[m_][n_], 0, 0, 0); }

__global__ __launch_bounds__(256, 3) void gemm1_proj(
    const unsigned short* __restrict__ A,
    const unsigned short* __restrict__ Bt,
    unsigned short* __restrict__ proj,
    unsigned short* __restrict__ swb,
    const float4* __restrict__ mwp,
    unsigned short* __restrict__ G,
    const int M, const int N, const int K)
{
    __shared__ __align__(16) char smem[32768];   // 2 x (8KB A + 8KB B)
    unsigned short* sA0 = (unsigned short*)smem;
    unsigned short* sB0 = (unsigned short*)(smem + 8192);
    unsigned short* sA1 = (unsigned short*)(smem + 16384);
    unsigned short* sB1 = (unsigned short*)(smem + 24576);
    const int tid  = threadIdx.x;
    const int wid  = tid >> 6;
    const int lane = tid & 63;

    const int flat = blockIdx.y * gridDim.x + blockIdx.x;
    const int xcd  = flat & 7;
    const int ii   = flat >> 3;
    const int bm   = ((xcd << 3) + (ii & 7)) * 128;
    const int bn   = (ii >> 3) * 128;

    const int wm = (wid >> 1) * 64;
    const int wn = (wid & 1) * 64;

    f32x4 acc[4][4];
#pragma unroll
    for (int m = 0; m < 4; m++)
#pragma unroll
        for (int n = 0; n < 4; n++) acc[m][n] = (f32x4){0.f, 0.f, 0.f, 0.f};

    const int r0 = wid * 32 + (lane >> 2);
    const int sl = ((lane & 3) ^ ((r0 >> 1) & 3)) * 8;
    const unsigned short* aP0 = A  + (size_t)(bm + r0)      * K + sl;
    const unsigned short* aP1 = A  + (size_t)(bm + r0 + 16) * K + sl;
    const unsigned short* bP0 = Bt + (size_t)(bn + r0)      * K + sl;
    const unsigned short* bP1 = Bt + (size_t)(bn + r0 + 16) * K + sl;
    unsigned short* wA0 = sA0 + wid * 1024;
    unsigned short* wB0 = sB0 + wid * 1024;
    unsigned short* wA1 = sA1 + wid * 1024;
    unsigned short* wB1 = sB1 + wid * 1024;

    const int fr  = lane & 15;
    const int h   = lane >> 4;
    const int rsl = (h ^ ((fr >> 1) & 3)) * 8;
    const int nt  = K >> 5;

    STAGE(0, wA0, wB0);
    STAGE(32, wA1, wB1);
    for (int t = 0; t < nt; t += 2) {
        SB0; WAITV4; SB0;
        BARR; SB0;
        COMPUTE(sA0, sB0);
        SB0; BARR; SB0;
        if (t + 2 < nt) {
            STAGE((t + 2) * 32, wA0, wB0);
            SB0; WAITV4; SB0;
        } else {
            SB0; WAITV0; SB0;
        }
        BARR; SB0;
        COMPUTE(sA1, sB1);
        SB0; BARR; SB0;
        if (t + 3 < nt) STAGE((t + 3) * 32, wA1, wB1);
    }

    int reg;
    if      (bn < 512)  reg = 0;
    else if (bn < 1024) reg = 1;
    else if (bn < 1536) reg = 2;
    else if (bn < 2048) reg = 3;
    else if (bn < 2560) reg = 2;
    else if (bn < 3072) reg = 1;
    else if (bn < 3584) reg = 4;
    else if (bn < 4096) reg = 3;
    else if (bn < 4352) reg = 5;
    else                reg = 6;

    if (reg == 6) {
        unsigned short* wp = (unsigned short*)(smem + wid * 2304);  // 16 x pitch 40
        const int sb = (bn + wn - 4352) >> 5;
#pragma unroll
        for (int m = 0; m < 4; m++) {
#pragma unroll
            for (int pr = 0; pr < 2; pr++)
#pragma unroll
                for (int r = 0; r < 4; r++) {
                    int row = bm + wm + m * 16 + h * 4 + r;
                    float m2 = mwp[row].z;
                    float up = acc[m][pr * 2][r];
                    float gt = acc[m][pr * 2 + 1][r];
                    wp[(h * 4 + r) * 40 + pr * 16 + fr] = f2b(m2 * up * silu_(gt));
                }
            {
                int lr = lane >> 2;
                int lc = (lane & 3) * 8;
                bf16x8 v = *(bf16x8*)(wp + lr * 40 + lc);
                int grow = bm + wm + m * 16 + lr;
                *(bf16x8*)(G + (size_t)grow * 2048 + 1024 + sb * 16 + lc) = v;
            }
        }
    } else {
        unsigned short* wp = (unsigned short*)(smem + wid * 2304);  // 16 x pitch72 bf16
        const int nsub = (reg == 5) ? 2 : 1;
#pragma unroll
        for (int m = 0; m < 4; m++) {
            for (int sub = 0; sub < nsub; sub++) {
#pragma unroll
                for (int n = 0; n < 4; n++)
#pragma unroll
                    for (int r = 0; r < 4; r++) {
                        float v = acc[m][n][r];
                        float o;
                        if      (reg == 0) o = tanh_(v);
                        else if (reg == 1) o = sigm_(v);
                        else if (reg == 2) o = silu_(v);
                        else if (reg == 3) o = v;
                        else if (reg == 4) o = sigm_(-v);
                        else {
                            float om = 3.14159265358979f * tanh_(v);
                            o = sub ? __sinf(om) : __cosf(om);
                        }
                        wp[(h * 4 + r) * 72 + n * 16 + fr] = f2b(o);
                    }
#pragma unroll
                for (int p = 0; p < 2; p++) {
                    int lr = p * 8 + (lane >> 3);
                    int lc = (lane & 7) * 8;
                    bf16x8 v = *(bf16x8*)(wp + lr * 72 + lc);
                    int grow = bm + wm + m * 16 + lr;
                    int gcol = bn + wn + lc;
                    if (sub == 0)
                        *(bf16x8*)(proj + (size_t)grow * N + gcol) = v;
                    else
                        *(bf16x8*)(swb + (size_t)grow * HALF_ + (gcol - 4096)) = v;
                }
            }
        }
    }
}

// ---------------------------------------------------------------- GEMM2: 128x64 tile
// Grid (N/64)x(M/128) = 16x64 = 1024 blocks -> 4 blocks/CU (vs 2 at 128x128).
// 4 waves (2Mx2N, each 64x32 out). 24KB dbuf. Counted vmcnt(3) pipeline (3 loads/tile).
__global__ __launch_bounds__(256, 3) void gemm2_f32(
    const unsigned short* __restrict__ A,
    const unsigned short* __restrict__ Bt,
    float* __restrict__ outp,
    const int M, const int N, const int K)
{
    __shared__ __align__(16) char smem[24576];
    unsigned short* sA0 = (unsigned short*)smem;              // 128x32 = 8KB
    unsigned short* sB0 = (unsigned short*)(smem + 8192);     //  64x32 = 4KB
    unsigned short* sA1 = (unsigned short*)(smem + 12288);
    unsigned short* sB1 = (unsigned short*)(smem + 20480);
    const int tid  = threadIdx.x;
    const int wid  = tid >> 6;
    const int lane = tid & 63;

    // XCD swizzle over 1024 blocks (bijective)
    const int flat = blockIdx.y * gridDim.x + blockIdx.x;
    const int xcd  = flat & 7;
    const int ii   = flat >> 3;
    const int bm   = ((xcd << 3) + (ii & 7)) * 128;
    const int bn   = (ii >> 3) * 64;

    const int wm = (wid >> 1) * 64;       // wave row offset (2 waves in M)
    const int wn = (wid & 1) * 32;        // wave col offset (2 waves in N)

    f32x4 acc[4][2];
#pragma unroll
    for (int m = 0; m < 4; m++)
#pragma unroll
        for (int n = 0; n < 2; n++) acc[m][n] = (f32x4){0.f, 0.f, 0.f, 0.f};

    // staging: A rows wid*32+(lane>>2) and +16; B rows wid*16+(lane>>2)
    const int rA = wid * 32 + (lane >> 2);
    const int slA = ((lane & 3) ^ ((rA >> 1) & 3)) * 8;
    const unsigned short* aP0 = A + (size_t)(bm + rA)      * K + slA;
    const unsigned short* aP1 = A + (size_t)(bm + rA + 16) * K + slA;
    const int rB = wid * 16 + (lane >> 2);
    const int slB = ((lane & 3) ^ ((rB >> 1) & 3)) * 8;
    const unsigned short* bP = Bt + (size_t)(bn + rB) * K + slB;
    unsigned short* wA0 = sA0 + wid * 1024;
    unsigned short* wB0 = sB0 + wid * 512;
    unsigned short* wA1 = sA1 + wid * 1024;
    unsigned short* wB1 = sB1 + wid * 512;

    const int fr  = lane & 15;
    const int h   = lane >> 4;
    const int rsl = (h ^ ((fr >> 1) & 3)) * 8;
    const int nt  = K >> 5;    // 64 (even)

#define STG2(kt_, dA, dB) {            \
    gload16(aP0 + (kt_), (dA));        \
    gload16(aP1 + (kt_), (dA) + 512);  \
    gload16(bP  + (kt_), (dB)); }

#define CMP2(sAr, sBr) {                                                               \
    bf16x8 af[4], bfv[2];                                                              \
    _Pragma("unroll")                                                                  \
    for (int m_ = 0; m_ < 4; m_++)                                                     \
        af[m_] = *(const bf16x8*)((sAr) + (wm + m_ * 16 + fr) * 32 + rsl);             \
    _Pragma("unroll")                                                                  \
    for (int n_ = 0; n_ < 2; n_++)                                                     \
        bfv[n_] = *(const bf16x8*)((sBr) + (wn + n_ * 16 + fr) * 32 + rsl);            \
    _Pragma("unroll")                                                                  \
    for (int m_ = 0; m_ < 4; m_++)                                                     \
        _Pragma("unroll")                                                              \
        for (int n_ = 0; n_ < 2; n_++)                                                 \
            acc[m_][n_] = __builtin_amdgcn_mfma_f32_16x16x32_bf16(af[m_], bfv[n_], acc[m_][n_], 0, 0, 0); }

    STG2(0, wA0, wB0);
    STG2(32, wA1, wB1);
    for (int t = 0; t < nt; t += 2) {
        SB0; WAITV3; SB0;               // tile t's 3 loads landed (t+1's in flight)
        BARR; SB0;
        CMP2(sA0, sB0);
        SB0; BARR; SB0;
        if (t + 2 < nt) {
            STG2((t + 2) * 32, wA0, wB0);
            SB0; WAITV3; SB0;
        } else {
            SB0; WAITV0; SB0;
        }
        BARR; SB0;
        CMP2(sA1, sB1);
        SB0; BARR; SB0;                 // also guards epilogue LDS reuse
        if (t + 3 < nt) STG2((t + 3) * 32, wA1, wB1);
    }
#undef STG2
#undef CMP2

    // epilogue: wave-private f32 patch 16 x pitch36 (2304B/wave), float4 stores
    float* wp = (float*)(smem + wid * 2304);
#pragma unroll
    for (int m = 0; m < 4; m++) {
#pragma unroll
        for (int n = 0; n < 2; n++)
#pragma unroll
            for (int r = 0; r < 4; r++)
                wp[(h * 4 + r) * 36 + n * 16 + fr] = acc[m][n][r];
#pragma unroll
        for (int rnd = 0; rnd < 2; rnd++) {
            int lr = rnd * 8 + (lane >> 3);
            int lc = (lane & 7) * 4;
            float4 v = *(float4*)&wp[lr * 36 + lc];
            int grow = bm + wm + m * 16 + lr;
            int gcol = bn + wn + lc;
            *(float4*)&outp[(size_t)grow * N + gcol] = v;
        }
    }
}

// ---------------------------------------------------------------- scan pass 1: chunk summaries
__global__ void scan_pass1(const unsigned short* __restrict__ proj, const unsigned short* __restrict__ swb,
                           float* __restrict__ rsP, float* __restrict__ rsY,
                           float4* __restrict__ ssM, float2* __restrict__ ssY) {
    const int c = blockIdx.x, b = blockIdx.y, z = blockIdx.z, tid = threadIdx.x;
    const int row0 = b * T_ + c * LC_;
    const unsigned short* base = proj + (size_t)row0 * N1_;
    if (z < 2) {
        const int s = z * 256 + tid;
        float P = 1.f, y = 0.f;
#pragma unroll 4
        for (int t = 0; t < LC_; t++) {
            const unsigned short* r = base + (size_t)t * N1_;
            float rf = b2f(r[s]);
            float rg = b2f(r[512 + s]);
            float rc = b2f(r[1024 + s]);
            y = rf * y + rg * rc;
            P *= rf;
        }
        int idx = (b * NCH_ + c) * S_ + s;
        rsP[idx] = P; rsY[idx] = y;
    } else {
        const int p = tid;
        const unsigned short* swr = swb + (size_t)row0 * HALF_;
        float m00 = 1.f, m01 = 0.f, m10 = 0.f, m11 = 1.f, y0 = 0.f, y1 = 0.f;
#pragma unroll 2
        for (int t = 0; t < LC_; t++) {
            const unsigned short* r = base + (size_t)t * N1_;
            float cw  = b2f(r[4096 + p]);
            float sw  = b2f(swr[(size_t)t * HALF_ + p]);
            float de  = b2f(r[3072 + p]);
            float dob = b2f(r[3328 + p]);
            float ge  = b2f(r[2560 + p]);
            float go  = b2f(r[2816 + p]);
            float ce  = b2f(r[2048 + p]);
            float co  = b2f(r[2304 + p]);
            float a = de * cw, bb = -de * sw, cc = dob * sw, dd = dob * cw;
            float ny0 = a * y0 + bb * y1 + ge * ce;
            float ny1 = cc * y0 + dd * y1 + go * co;
            y0 = ny0; y1 = ny1;
            float n00 = a * m00 + bb * m10, n01 = a * m01 + bb * m11;
            float n10 = cc * m00 + dd * m10, n11 = cc * m01 + dd * m11;
            m00 = n00; m01 = n01; m10 = n10; m11 = n11;
        }
        int idx = (b * NCH_ + c) * HALF_ + p;
        ssM[idx] = (float4){m00, m01, m10, m11};
        ssY[idx] = (float2){y0, y1};
    }
}

// ---------------------------------------------------------------- scan pass 2: chunk-start states
__global__ void scan_pass2(const float* __restrict__ rsP, const float* __restrict__ rsY,
                           const float4* __restrict__ ssM, const float2* __restrict__ ssY,
                           const float* __restrict__ read_init, const float* __restrict__ stable_init,
                           float* __restrict__ rsStart, float2* __restrict__ ssStart) {
    int id = blockIdx.x * 256 + threadIdx.x;
    if (id < B_ * S_) {
        int b = id / S_, s = id % S_;
        float st = read_init[s];
        for (int c = 0; c < NCH_; c++) {
            int idx = (b * NCH_ + c) * S_ + s;
            rsStart[idx] = st;
            st = rsP[idx] * st + rsY[idx];
        }
    } else {
        id -= B_ * S_;
        int b = id / HALF_, p = id % HALF_;
        float y0 = stable_init[p], y1 = stable_init[p + HALF_];
        for (int c = 0; c < NCH_; c++) {
            int idx = (b * NCH_ + c) * HALF_ + p;
            ssStart[idx] = (float2){y0, y1};
            float4 m = ssM[idx]; float2 u = ssY[idx];
            float ny0 = m.x * y0 + m.y * y1 + u.x;
            float ny1 = m.z * y0 + m.w * y1 + u.y;
            y0 = ny0; y1 = ny1;
        }
    }
}

// ---------------------------------------------------------------- scan pass 3: recompute + emit G
__global__ void scan_pass3(const unsigned short* __restrict__ proj, const unsigned short* __restrict__ swb,
                           const float* __restrict__ rsStart, const float2* __restrict__ ssStart,
                           const float4* __restrict__ mw, unsigned short* __restrict__ G) {
    const int c = blockIdx.x, b = blockIdx.y, z = blockIdx.z, tid = threadIdx.x;
    const int row0 = b * T_ + c * LC_;
    const unsigned short* base = proj + (size_t)row0 * N1_;
    if (z < 2) {
        const int s = z * 256 + tid;
        float rs = rsStart[(b * NCH_ + c) * S_ + s];
#pragma unroll 4
        for (int t = 0; t < LC_; t++) {
            const size_t row = row0 + t;
            const unsigned short* r = base + (size_t)t * N1_;
            float rf = b2f(r[s]);
            float rg = b2f(r[512 + s]);
            float rc = b2f(r[1024 + s]);
            rs = rf * rs + rg * rc;
            float q  = b2f(r[1536 + s]);
            float zz = q * rs;
            G[row * 2048 + s] = f2b(mw[row].x * silu_(zz));
        }
    } else {
        const int p = tid;
        const unsigned short* swr = swb + (size_t)row0 * HALF_;
        float2 st = ssStart[(b * NCH_ + c) * HALF_ + p];
        float y0 = st.x, y1 = st.y;
#pragma unroll 2
        for (int t = 0; t < LC_; t++) {
            const size_t row = row0 + t;
            const unsigned short* r = base + (size_t)t * N1_;
            float cw  = b2f(r[4096 + p]);
            float sw  = b2f(swr[(size_t)t * HALF_ + p]);
            float de  = b2f(r[3072 + p]);
            float dob = b2f(r[3328 + p]);
            float ge  = b2f(r[2560 + p]);
            float go  = b2f(r[2816 + p]);
            float ce  = b2f(r[2048 + p]);
            float co  = b2f(r[2304 + p]);
            float a = de * cw, bb = -de * sw, cc = dob * sw, dd = dob * cw;
            float ny0 = a * y0 + bb * y1 + ge * ce;
            float ny1 = cc * y0 + dd * y1 + go * co;
            y0 = ny0; y1 = ny1;
            float qe = b2f(r[3584 + p]);
            float qo = b2f(r[3840 + p]);
            float w1v = mw[row].y;
            G[row * 2048 + 512 + p] = f2b(w1v * silu_(qe * y0));
            G[row * 2048 + 768 + p] = f2b(w1v * silu_(qo * y1));
        }
    }
}

// ================================================================ host
extern "C" void kernel_launch(void* const* d_in, const int* in_sizes, int n_in,
                              void* d_out, int out_size, void* d_ws, size_t ws_size,
                              hipStream_t stream) {
    const float* x       = (const float*)d_in[0];
    const float* W_rf    = (const float*)d_in[1];
    const float* W_ri    = (const float*)d_in[2];
    const float* W_rv    = (const float*)d_in[3];
    const float* W_rq    = (const float*)d_in[4];
    const float* W_ro    = (const float*)d_in[5];
    const float* W_sw    = (const float*)d_in[6];
    const float* W_sg    = (const float*)d_in[7];
    const float* W_som   = (const float*)d_in[8];
    const float* W_sd    = (const float*)d_in[9];
    const float* W_sq    = (const float*)d_in[10];
    const float* W_so    = (const float*)d_in[11];
    const float* W_up    = (const float*)d_in[12];
    const float* W_gate  = (const float*)d_in[13];
    const float* W_down  = (const float*)d_in[14];
    const float* W_mix   = (const float*)d_in[15];
    const float* read_init   = (const float*)d_in[16];
    const float* stable_init = (const float*)d_in[17];

    char* ws = (char*)d_ws;
    size_t off = 0;
    auto alloc = [&](size_t bytes) -> void* {
        void* p = ws + off;
        off = (off + bytes + 255) & ~(size_t)255;
        return p;
    };
    unsigned short* xb   = (unsigned short*)alloc((size_t)BT_ * H_ * 2);
    unsigned short* w1   = (unsigned short*)alloc((size_t)N1_ * K1_ * 2);
    unsigned short* w2   = (unsigned short*)alloc((size_t)N2_ * K2_ * 2);
    unsigned short* proj = (unsigned short*)alloc((size_t)BT_ * N1_ * 2);
    unsigned short* swb  = (unsigned short*)alloc((size_t)BT_ * HALF_ * 2);
    float4*         mw   = (float4*)alloc((size_t)BT_ * 16);
    unsigned short* G    = (unsigned short*)alloc((size_t)BT_ * 2048 * 2);
    float*  rsP     = (float*) alloc((size_t)B_ * NCH_ * S_ * 4);
    float*  rsY     = (float*) alloc((size_t)B_ * NCH_ * S_ * 4);
    float4* ssM     = (float4*)alloc((size_t)B_ * NCH_ * HALF_ * 16);
    float2* ssY     = (float2*)alloc((size_t)B_ * NCH_ * HALF_ * 8);
    float*  rsStart = (float*) alloc((size_t)B_ * NCH_ * S_ * 4);
    float2* ssStart = (float2*)alloc((size_t)B_ * NCH_ * HALF_ * 8);
    if (off > ws_size) return;

    prep_x<<<BT_ / 4, 256, 0, stream>>>(x, W_mix, xb, mw);

    TOps ops;
    int i = 0;
    auto add = [&](const float* s, int Kw, int Nw, int n_ofs, int k_ofs, int which, int ilv) {
        ops.v[i].src = s; ops.v[i].Kw = Kw; ops.v[i].Nw = Nw;
        ops.v[i].n_ofs = n_ofs; ops.v[i].k_ofs = k_ofs; ops.v[i].which = which;
        ops.v[i].ilv = ilv; i++;
    };
    add(W_rf,  1024,  512,    0,    0, 0, 0);
    add(W_ri,  1024,  512,  512,    0, 0, 0);
    add(W_rv,  1024,  512, 1024,    0, 0, 0);
    add(W_rq,  1024,  512, 1536,    0, 0, 0);
    add(W_sw,  1024,  512, 2048,    0, 0, 0);
    add(W_sg,  1024,  512, 2560,    0, 0, 0);
    add(W_sd,  1024,  512, 3072,    0, 0, 0);
    add(W_sq,  1024,  512, 3584,    0, 0, 0);
    add(W_som, 1024,  256, 4096,    0, 0, 0);
    add(W_up,  1024, 1024, 4352,    0, 0, 1);   // interleaved: [up16|gate16] superblocks
    add(W_gate,1024, 1024, 4352,    0, 0, 2);
    add(W_ro,   512, 1024,    0,    0, 1, 0);
    add(W_so,   512, 1024,    0,  512, 1, 0);
    add(W_down,1024, 1024,    0, 1024, 1, 0);
    pack_w_kernel<<<dim3(32, 32, 14), 256, 0, stream>>>(ops, w1, w2);

    gemm1_proj<<<dim3(N1_ / 128, BT_ / 128), 256, 0, stream>>>(
        xb, w1, proj, swb, mw, G, BT_, N1_, K1_);

    scan_pass1<<<dim3(NCH_, B_, 3), 256, 0, stream>>>(proj, swb, rsP, rsY, ssM, ssY);
    scan_pass2<<<12, 256, 0, stream>>>(rsP, rsY, ssM, ssY, read_init, stable_init, rsStart, ssStart);
    scan_pass3<<<dim3(NCH_, B_, 3), 256, 0, stream>>>(proj, swb, rsStart, ssStart, mw, G);

    gemm2_f32<<<dim3(N2_ / 64, BT_ / 128), 256, 0, stream>>>(
        G, w2, (float*)d_out, BT_, N2_, K2_);
}

// Round 14
// 232.260 us; speedup vs baseline: 1.0634x; 1.0634x over previous
//
#include <hip/hip_runtime.h>

#define B_    4
#define T_    2048
#define H_    1024
#define S_    512
#define HALF_ 256
#define LOC_  1024
#define BT_   8192          // B*T rows
#define N1_   6400          // proj cols: 8*512 + 256 + 1024 + 1024 (up/gate interleaved)
#define K1_   1024
#define N2_   1024
#define K2_   2048
#define NCH_  32            // scan chunks
#define LC_   64            // chunk length (T_/NCH_)

typedef __attribute__((ext_vector_type(8))) short  bf16x8;
typedef __attribute__((ext_vector_type(4))) float  f32x4;
typedef __attribute__((ext_vector_type(4))) unsigned short u16x4;

__device__ __forceinline__ float b2f(unsigned short u) {
    union { unsigned i; float f; } v; v.i = ((unsigned)u) << 16; return v.f;
}
__device__ __forceinline__ unsigned short f2b(float f) {
    union { float f; unsigned i; } v; v.f = f;
    unsigned r = v.i + 0x7fffu + ((v.i >> 16) & 1u);
    return (unsigned short)(r >> 16);
}
__device__ __forceinline__ float rcp_(float x) { return __builtin_amdgcn_rcpf(x); }
__device__ __forceinline__ float sigm_(float v) { return rcp_(1.f + __expf(-v)); }
__device__ __forceinline__ float silu_(float v) { return v * rcp_(1.f + __expf(-v)); }
__device__ __forceinline__ float tanh_(float v) { return 1.f - 2.f * rcp_(1.f + __expf(2.f * v)); }

__device__ __forceinline__ void gload16(const void* g, void* l) {
    __builtin_amdgcn_global_load_lds(
        (const __attribute__((address_space(1))) void*)g,
        (__attribute__((address_space(3))) void*)l,
        16, 0, 0);
}

#define SB0    __builtin_amdgcn_sched_barrier(0)
#define BARR   __builtin_amdgcn_s_barrier()
#define WAITV4 asm volatile("s_waitcnt vmcnt(4)" ::: "memory")
#define WAITV0 asm volatile("s_waitcnt vmcnt(0)" ::: "memory")

// ---------------------------------------------------------------- fused pack_x + mix
__global__ void prep_x(const float* __restrict__ x, const float* __restrict__ Wm,
                       unsigned short* __restrict__ xb, float4* __restrict__ mw) {
    const int row  = blockIdx.x * 4 + (threadIdx.x >> 6);
    const int lane = threadIdx.x & 63;
    const float4* xr = (const float4*)(x + (size_t)row * H_);
    u16x4* xbr = (u16x4*)(xb + (size_t)row * H_);
    float s0 = 0.f, s1 = 0.f, s2 = 0.f;
#pragma unroll
    for (int p = 0; p < 4; p++) {
        const int k4 = p * 64 + lane;
        float4 v = xr[k4];
        u16x4 u;
        u.x = f2b(v.x); u.y = f2b(v.y); u.z = f2b(v.z); u.w = f2b(v.w);
        xbr[k4] = u;
        const int k3 = k4 * 12;
        s0 += v.x * Wm[k3 + 0] + v.y * Wm[k3 + 3] + v.z * Wm[k3 + 6] + v.w * Wm[k3 + 9];
        s1 += v.x * Wm[k3 + 1] + v.y * Wm[k3 + 4] + v.z * Wm[k3 + 7] + v.w * Wm[k3 + 10];
        s2 += v.x * Wm[k3 + 2] + v.y * Wm[k3 + 5] + v.z * Wm[k3 + 8] + v.w * Wm[k3 + 11];
    }
#pragma unroll
    for (int off = 32; off; off >>= 1) {
        s0 += __shfl_down(s0, off);
        s1 += __shfl_down(s1, off);
        s2 += __shfl_down(s2, off);
    }
    if (lane == 0) {
        float m = fmaxf(s0, fmaxf(s1, s2));
        float e0 = __expf(s0 - m), e1 = __expf(s1 - m), e2 = __expf(s2 - m);
        float inv = 1.f / (e0 + e1 + e2);
        mw[row] = (float4){ e0 * inv, e1 * inv, e2 * inv, 0.f };
    }
}

// ------------------------------------------------- transpose-pack weights to [n][k] bf16
// ilv: 0 = plain; 1 = up-half of 32-col superblock; 2 = gate-half.
struct TOp { const float* src; int Kw; int Nw; int n_ofs; int k_ofs; int which; int ilv; };
struct TOps { TOp v[14]; };

__global__ void pack_w_kernel(TOps ops, unsigned short* __restrict__ w1, unsigned short* __restrict__ w2) {
    TOp op = ops.v[blockIdx.z];
    int kt = blockIdx.x * 32, nt = blockIdx.y * 32;
    if (kt >= op.Kw || nt >= op.Nw) return;
    __shared__ float tile[32][33];
    int tx = threadIdx.x & 31, ty = threadIdx.x >> 5;   // 32 x 8
#pragma unroll
    for (int r = 0; r < 4; r++) {
        int k = kt + ty + r * 8;
        tile[ty + r * 8][tx] = op.src[(size_t)k * op.Nw + nt + tx];
    }
    __syncthreads();
    unsigned short* dst = op.which ? w2 : w1;
    int stride = op.which ? K2_ : K1_;
#pragma unroll
    for (int r = 0; r < 4; r++) {
        int n = nt + ty + r * 8;
        int dcol;
        if (op.ilv)
            dcol = op.n_ofs + ((n >> 4) << 5) + ((op.ilv == 2) ? 16 : 0) + (n & 15);
        else
            dcol = op.n_ofs + n;
        dst[(size_t)dcol * stride + op.k_ofs + kt + tx] = f2b(tile[tx][ty + r * 8]);
    }
}

// ---------------------------------------------------------------- shared GEMM macros
#define STAGE(kt_, dA, dB) {          \
    gload16(aP0 + (kt_), (dA));       \
    gload16(aP1 + (kt_), (dA) + 512); \
    gload16(bP0 + (kt_), (dB));       \
    gload16(bP1 + (kt_), (dB) + 512); }

#define COMPUTE(sAr, sBr) {                                                            \
    bf16x8 af[4], bfv[4];                                                              \
    _Pragma("unroll")                                                                  \
    for (int m_ = 0; m_ < 4; m_++)                                                     \
        af[m_] = *(const bf16x8*)((sAr) + (wm + m_ * 16 + fr) * 32 + rsl);             \
    _Pragma("unroll")                                                                  \
    for (int n_ = 0; n_ < 4; n_++)                                                     \
        bfv[n_] = *(const bf16x8*)((sBr) + (wn + n_ * 16 + fr) * 32 + rsl);            \
    _Pragma("unroll")                                                                  \
    for (int m_ = 0; m_ < 4; m_++)                                                     \
        _Pragma("unroll")                                                              \
        for (int n_ = 0; n_ < 4; n_++)                                                 \
            acc[m_][n_] = __builtin_amdgcn_mfma_f32_16x16x32_bf16(af[m_], bfv[n_], acc[m_][n_], 0, 0, 0); }

// ---------------------------------------------------------------- GEMM1 (R12-proven)
// Counted-vmcnt double-buffer, XCD-aware bijective swizzle, wave-private epilogue.
// Regions: 0=tanh 1=sigm 2=silu 3=id 4=sigm(-v) 5=som(cos/sin)
//          6=fused local branch: G = mw.z * up * silu(gate)  (up/gate interleaved cols)
__global__ __launch_bounds__(256, 3) void gemm1_proj(
    const unsigned short* __restrict__ A,
    const unsigned short* __restrict__ Bt,
    unsigned short* __restrict__ proj,
    unsigned short* __restrict__ swb,
    const float4* __restrict__ mwp,
    unsigned short* __restrict__ G,
    const int M, const int N, const int K)
{
    __shared__ __align__(16) char smem[32768];   // 2 x (8KB A + 8KB B)
    unsigned short* sA0 = (unsigned short*)smem;
    unsigned short* sB0 = (unsigned short*)(smem + 8192);
    unsigned short* sA1 = (unsigned short*)(smem + 16384);
    unsigned short* sB1 = (unsigned short*)(smem + 24576);
    const int tid  = threadIdx.x;
    const int wid  = tid >> 6;
    const int lane = tid & 63;

    const int flat = blockIdx.y * gridDim.x + blockIdx.x;
    const int xcd  = flat & 7;
    const int ii   = flat >> 3;
    const int bm   = ((xcd << 3) + (ii & 7)) * 128;
    const int bn   = (ii >> 3) * 128;

    const int wm = (wid >> 1) * 64;
    const int wn = (wid & 1) * 64;

    f32x4 acc[4][4];
#pragma unroll
    for (int m = 0; m < 4; m++)
#pragma unroll
        for (int n = 0; n < 4; n++) acc[m][n] = (f32x4){0.f, 0.f, 0.f, 0.f};

    const int r0 = wid * 32 + (lane >> 2);
    const int sl = ((lane & 3) ^ ((r0 >> 1) & 3)) * 8;
    const unsigned short* aP0 = A  + (size_t)(bm + r0)      * K + sl;
    const unsigned short* aP1 = A  + (size_t)(bm + r0 + 16) * K + sl;
    const unsigned short* bP0 = Bt + (size_t)(bn + r0)      * K + sl;
    const unsigned short* bP1 = Bt + (size_t)(bn + r0 + 16) * K + sl;
    unsigned short* wA0 = sA0 + wid * 1024;
    unsigned short* wB0 = sB0 + wid * 1024;
    unsigned short* wA1 = sA1 + wid * 1024;
    unsigned short* wB1 = sB1 + wid * 1024;

    const int fr  = lane & 15;
    const int h   = lane >> 4;
    const int rsl = (h ^ ((fr >> 1) & 3)) * 8;
    const int nt  = K >> 5;

    STAGE(0, wA0, wB0);
    STAGE(32, wA1, wB1);
    for (int t = 0; t < nt; t += 2) {
        SB0; WAITV4; SB0;
        BARR; SB0;
        COMPUTE(sA0, sB0);
        SB0; BARR; SB0;
        if (t + 2 < nt) {
            STAGE((t + 2) * 32, wA0, wB0);
            SB0; WAITV4; SB0;
        } else {
            SB0; WAITV0; SB0;
        }
        BARR; SB0;
        COMPUTE(sA1, sB1);
        SB0; BARR; SB0;
        if (t + 3 < nt) STAGE((t + 3) * 32, wA1, wB1);
    }

    int reg;
    if      (bn < 512)  reg = 0;
    else if (bn < 1024) reg = 1;
    else if (bn < 1536) reg = 2;
    else if (bn < 2048) reg = 3;
    else if (bn < 2560) reg = 2;
    else if (bn < 3072) reg = 1;
    else if (bn < 3584) reg = 4;
    else if (bn < 4096) reg = 3;
    else if (bn < 4352) reg = 5;
    else                reg = 6;

    if (reg == 6) {
        unsigned short* wp = (unsigned short*)(smem + wid * 2304);  // 16 x pitch 40
        const int sb = (bn + wn - 4352) >> 5;
#pragma unroll
        for (int m = 0; m < 4; m++) {
#pragma unroll
            for (int pr = 0; pr < 2; pr++)
#pragma unroll
                for (int r = 0; r < 4; r++) {
                    int row = bm + wm + m * 16 + h * 4 + r;
                    float m2 = mwp[row].z;
                    float up = acc[m][pr * 2][r];
                    float gt = acc[m][pr * 2 + 1][r];
                    wp[(h * 4 + r) * 40 + pr * 16 + fr] = f2b(m2 * up * silu_(gt));
                }
            {
                int lr = lane >> 2;
                int lc = (lane & 3) * 8;
                bf16x8 v = *(bf16x8*)(wp + lr * 40 + lc);
                int grow = bm + wm + m * 16 + lr;
                *(bf16x8*)(G + (size_t)grow * 2048 + 1024 + sb * 16 + lc) = v;
            }
        }
    } else {
        unsigned short* wp = (unsigned short*)(smem + wid * 2304);  // 16 x pitch72 bf16
        const int nsub = (reg == 5) ? 2 : 1;
#pragma unroll
        for (int m = 0; m < 4; m++) {
            for (int sub = 0; sub < nsub; sub++) {
#pragma unroll
                for (int n = 0; n < 4; n++)
#pragma unroll
                    for (int r = 0; r < 4; r++) {
                        float v = acc[m][n][r];
                        float o;
                        if      (reg == 0) o = tanh_(v);
                        else if (reg == 1) o = sigm_(v);
                        else if (reg == 2) o = silu_(v);
                        else if (reg == 3) o = v;
                        else if (reg == 4) o = sigm_(-v);
                        else {
                            float om = 3.14159265358979f * tanh_(v);
                            o = sub ? __sinf(om) : __cosf(om);
                        }
                        wp[(h * 4 + r) * 72 + n * 16 + fr] = f2b(o);
                    }
#pragma unroll
                for (int p = 0; p < 2; p++) {
                    int lr = p * 8 + (lane >> 3);
                    int lc = (lane & 7) * 8;
                    bf16x8 v = *(bf16x8*)(wp + lr * 72 + lc);
                    int grow = bm + wm + m * 16 + lr;
                    int gcol = bn + wn + lc;
                    if (sub == 0)
                        *(bf16x8*)(proj + (size_t)grow * N + gcol) = v;
                    else
                        *(bf16x8*)(swb + (size_t)grow * HALF_ + (gcol - 4096)) = v;
                }
            }
        }
    }
}

// ---------------------------------------------------------------- GEMM2 (R11-proven)
// 128x128 tile, static double-buffer, prefetch-before-compute, one __syncthreads
// per K-step, XCD swizzle, wave-private f32 vectorized epilogue.
__global__ __launch_bounds__(256, 3) void gemm2_f32(
    const unsigned short* __restrict__ A,
    const unsigned short* __restrict__ Bt,
    float* __restrict__ outp,
    const int M, const int N, const int K)
{
    __shared__ __align__(16) char smem[32768];   // 2 x (8KB A + 8KB B)
    unsigned short* sA0 = (unsigned short*)smem;
    unsigned short* sB0 = (unsigned short*)(smem + 8192);
    unsigned short* sA1 = (unsigned short*)(smem + 16384);
    unsigned short* sB1 = (unsigned short*)(smem + 24576);
    const int tid  = threadIdx.x;
    const int wid  = tid >> 6;
    const int lane = tid & 63;

    const int flat = blockIdx.y * gridDim.x + blockIdx.x;
    const int xcd  = flat & 7;
    const int ii   = flat >> 3;
    const int bm   = ((xcd << 3) + (ii & 7)) * 128;
    const int bn   = (ii >> 3) * 128;

    const int wm = (wid >> 1) * 64;
    const int wn = (wid & 1) * 64;

    f32x4 acc[4][4];
#pragma unroll
    for (int m = 0; m < 4; m++)
#pragma unroll
        for (int n = 0; n < 4; n++) acc[m][n] = (f32x4){0.f, 0.f, 0.f, 0.f};

    const int r0 = wid * 32 + (lane >> 2);
    const int sl = ((lane & 3) ^ ((r0 >> 1) & 3)) * 8;
    const unsigned short* aP0 = A  + (size_t)(bm + r0)      * K + sl;
    const unsigned short* aP1 = A  + (size_t)(bm + r0 + 16) * K + sl;
    const unsigned short* bP0 = Bt + (size_t)(bn + r0)      * K + sl;
    const unsigned short* bP1 = Bt + (size_t)(bn + r0 + 16) * K + sl;
    unsigned short* wA0 = sA0 + wid * 1024;
    unsigned short* wB0 = sB0 + wid * 1024;
    unsigned short* wA1 = sA1 + wid * 1024;
    unsigned short* wB1 = sB1 + wid * 1024;

    const int fr  = lane & 15;
    const int h   = lane >> 4;
    const int rsl = (h ^ ((fr >> 1) & 3)) * 8;
    const int nt  = K >> 5;   // 64 (even)

    STAGE(0, wA0, wB0);
    __syncthreads();
    for (int t = 0; t < nt; t += 2) {
        STAGE((t + 1) * 32, wA1, wB1);   // prefetch flies during compute of buf0
        COMPUTE(sA0, sB0);
        __syncthreads();                 // drains prefetch + protects buf0 rewrite
        if (t + 2 < nt) STAGE((t + 2) * 32, wA0, wB0);
        COMPUTE(sA1, sB1);
        __syncthreads();
    }

    float* wp = (float*)(smem + wid * 4608);
#pragma unroll
    for (int m = 0; m < 4; m++) {
#pragma unroll
        for (int n = 0; n < 4; n++)
#pragma unroll
            for (int r = 0; r < 4; r++)
                wp[(h * 4 + r) * 68 + n * 16 + fr] = acc[m][n][r];
#pragma unroll
        for (int rnd = 0; rnd < 4; rnd++) {
            int lr = rnd * 4 + (lane >> 4);
            int lc = (lane & 15) * 4;
            float4 v = *(float4*)&wp[lr * 68 + lc];
            int grow = bm + wm + m * 16 + lr;
            int gcol = bn + wn + lc;
            *(float4*)&outp[(size_t)grow * N + gcol] = v;
        }
    }
}

// ---------------------------------------------------------------- scan pass 1: chunk summaries
__global__ void scan_pass1(const unsigned short* __restrict__ proj, const unsigned short* __restrict__ swb,
                           float* __restrict__ rsP, float* __restrict__ rsY,
                           float4* __restrict__ ssM, float2* __restrict__ ssY) {
    const int c = blockIdx.x, b = blockIdx.y, z = blockIdx.z, tid = threadIdx.x;
    const int row0 = b * T_ + c * LC_;
    const unsigned short* base = proj + (size_t)row0 * N1_;
    if (z < 2) {
        const int s = z * 256 + tid;
        float P = 1.f, y = 0.f;
#pragma unroll 4
        for (int t = 0; t < LC_; t++) {
            const unsigned short* r = base + (size_t)t * N1_;
            float rf = b2f(r[s]);
            float rg = b2f(r[512 + s]);
            float rc = b2f(r[1024 + s]);
            y = rf * y + rg * rc;
            P *= rf;
        }
        int idx = (b * NCH_ + c) * S_ + s;
        rsP[idx] = P; rsY[idx] = y;
    } else {
        const int p = tid;
        const unsigned short* swr = swb + (size_t)row0 * HALF_;
        float m00 = 1.f, m01 = 0.f, m10 = 0.f, m11 = 1.f, y0 = 0.f, y1 = 0.f;
#pragma unroll 2
        for (int t = 0; t < LC_; t++) {
            const unsigned short* r = base + (size_t)t * N1_;
            float cw  = b2f(r[4096 + p]);
            float sw  = b2f(swr[(size_t)t * HALF_ + p]);
            float de  = b2f(r[3072 + p]);
            float dob = b2f(r[3328 + p]);
            float ge  = b2f(r[2560 + p]);
            float go  = b2f(r[2816 + p]);
            float ce  = b2f(r[2048 + p]);
            float co  = b2f(r[2304 + p]);
            float a = de * cw, bb = -de * sw, cc = dob * sw, dd = dob * cw;
            float ny0 = a * y0 + bb * y1 + ge * ce;
            float ny1 = cc * y0 + dd * y1 + go * co;
            y0 = ny0; y1 = ny1;
            float n00 = a * m00 + bb * m10, n01 = a * m01 + bb * m11;
            float n10 = cc * m00 + dd * m10, n11 = cc * m01 + dd * m11;
            m00 = n00; m01 = n01; m10 = n10; m11 = n11;
        }
        int idx = (b * NCH_ + c) * HALF_ + p;
        ssM[idx] = (float4){m00, m01, m10, m11};
        ssY[idx] = (float2){y0, y1};
    }
}

// ---------------------------------------------------------------- scan pass 2: chunk-start states
__global__ void scan_pass2(const float* __restrict__ rsP, const float* __restrict__ rsY,
                           const float4* __restrict__ ssM, const float2* __restrict__ ssY,
                           const float* __restrict__ read_init, const float* __restrict__ stable_init,
                           float* __restrict__ rsStart, float2* __restrict__ ssStart) {
    int id = blockIdx.x * 256 + threadIdx.x;
    if (id < B_ * S_) {
        int b = id / S_, s = id % S_;
        float st = read_init[s];
        for (int c = 0; c < NCH_; c++) {
            int idx = (b * NCH_ + c) * S_ + s;
            rsStart[idx] = st;
            st = rsP[idx] * st + rsY[idx];
        }
    } else {
        id -= B_ * S_;
        int b = id / HALF_, p = id % HALF_;
        float y0 = stable_init[p], y1 = stable_init[p + HALF_];
        for (int c = 0; c < NCH_; c++) {
            int idx = (b * NCH_ + c) * HALF_ + p;
            ssStart[idx] = (float2){y0, y1};
            float4 m = ssM[idx]; float2 u = ssY[idx];
            float ny0 = m.x * y0 + m.y * y1 + u.x;
            float ny1 = m.z * y0 + m.w * y1 + u.y;
            y0 = ny0; y1 = ny1;
        }
    }
}

// ---------------------------------------------------------------- scan pass 3: recompute + emit G
__global__ void scan_pass3(const unsigned short* __restrict__ proj, const unsigned short* __restrict__ swb,
                           const float* __restrict__ rsStart, const float2* __restrict__ ssStart,
                           const float4* __restrict__ mw, unsigned short* __restrict__ G) {
    const int c = blockIdx.x, b = blockIdx.y, z = blockIdx.z, tid = threadIdx.x;
    const int row0 = b * T_ + c * LC_;
    const unsigned short* base = proj + (size_t)row0 * N1_;
    if (z < 2) {
        const int s = z * 256 + tid;
        float rs = rsStart[(b * NCH_ + c) * S_ + s];
#pragma unroll 4
        for (int t = 0; t < LC_; t++) {
            const size_t row = row0 + t;
            const unsigned short* r = base + (size_t)t * N1_;
            float rf = b2f(r[s]);
            float rg = b2f(r[512 + s]);
            float rc = b2f(r[1024 + s]);
            rs = rf * rs + rg * rc;
            float q  = b2f(r[1536 + s]);
            float zz = q * rs;
            G[row * 2048 + s] = f2b(mw[row].x * silu_(zz));
        }
    } else {
        const int p = tid;
        const unsigned short* swr = swb + (size_t)row0 * HALF_;
        float2 st = ssStart[(b * NCH_ + c) * HALF_ + p];
        float y0 = st.x, y1 = st.y;
#pragma unroll 2
        for (int t = 0; t < LC_; t++) {
            const size_t row = row0 + t;
            const unsigned short* r = base + (size_t)t * N1_;
            float cw  = b2f(r[4096 + p]);
            float sw  = b2f(swr[(size_t)t * HALF_ + p]);
            float de  = b2f(r[3072 + p]);
            float dob = b2f(r[3328 + p]);
            float ge  = b2f(r[2560 + p]);
            float go  = b2f(r[2816 + p]);
            float ce  = b2f(r[2048 + p]);
            float co  = b2f(r[2304 + p]);
            float a = de * cw, bb = -de * sw, cc = dob * sw, dd = dob * cw;
            float ny0 = a * y0 + bb * y1 + ge * ce;
            float ny1 = cc * y0 + dd * y1 + go * co;
            y0 = ny0; y1 = ny1;
            float qe = b2f(r[3584 + p]);
            float qo = b2f(r[3840 + p]);
            float w1v = mw[row].y;
            G[row * 2048 + 512 + p] = f2b(w1v * silu_(qe * y0));
            G[row * 2048 + 768 + p] = f2b(w1v * silu_(qo * y1));
        }
    }
}

// ================================================================ host
extern "C" void kernel_launch(void* const* d_in, const int* in_sizes, int n_in,
                              void* d_out, int out_size, void* d_ws, size_t ws_size,
                              hipStream_t stream) {
    const float* x       = (const float*)d_in[0];
    const float* W_rf    = (const float*)d_in[1];
    const float* W_ri    = (const float*)d_in[2];
    const float* W_rv    = (const float*)d_in[3];
    const float* W_rq    = (const float*)d_in[4];
    const float* W_ro    = (const float*)d_in[5];
    const float* W_sw    = (const float*)d_in[6];
    const float* W_sg    = (const float*)d_in[7];
    const float* W_som   = (const float*)d_in[8];
    const float* W_sd    = (const float*)d_in[9];
    const float* W_sq    = (const float*)d_in[10];
    const float* W_so    = (const float*)d_in[11];
    const float* W_up    = (const float*)d_in[12];
    const float* W_gate  = (const float*)d_in[13];
    const float* W_down  = (const float*)d_in[14];
    const float* W_mix   = (const float*)d_in[15];
    const float* read_init   = (const float*)d_in[16];
    const float* stable_init = (const float*)d_in[17];

    char* ws = (char*)d_ws;
    size_t off = 0;
    auto alloc = [&](size_t bytes) -> void* {
        void* p = ws + off;
        off = (off + bytes + 255) & ~(size_t)255;
        return p;
    };
    unsigned short* xb   = (unsigned short*)alloc((size_t)BT_ * H_ * 2);
    unsigned short* w1   = (unsigned short*)alloc((size_t)N1_ * K1_ * 2);
    unsigned short* w2   = (unsigned short*)alloc((size_t)N2_ * K2_ * 2);
    unsigned short* proj = (unsigned short*)alloc((size_t)BT_ * N1_ * 2);
    unsigned short* swb  = (unsigned short*)alloc((size_t)BT_ * HALF_ * 2);
    float4*         mw   = (float4*)alloc((size_t)BT_ * 16);
    unsigned short* G    = (unsigned short*)alloc((size_t)BT_ * 2048 * 2);
    float*  rsP     = (float*) alloc((size_t)B_ * NCH_ * S_ * 4);
    float*  rsY     = (float*) alloc((size_t)B_ * NCH_ * S_ * 4);
    float4* ssM     = (float4*)alloc((size_t)B_ * NCH_ * HALF_ * 16);
    float2* ssY     = (float2*)alloc((size_t)B_ * NCH_ * HALF_ * 8);
    float*  rsStart = (float*) alloc((size_t)B_ * NCH_ * S_ * 4);
    float2* ssStart = (float2*)alloc((size_t)B_ * NCH_ * HALF_ * 8);
    if (off > ws_size) return;

    prep_x<<<BT_ / 4, 256, 0, stream>>>(x, W_mix, xb, mw);

    TOps ops;
    int i = 0;
    auto add = [&](const float* s, int Kw, int Nw, int n_ofs, int k_ofs, int which, int ilv) {
        ops.v[i].src = s; ops.v[i].Kw = Kw; ops.v[i].Nw = Nw;
        ops.v[i].n_ofs = n_ofs; ops.v[i].k_ofs = k_ofs; ops.v[i].which = which;
        ops.v[i].ilv = ilv; i++;
    };
    add(W_rf,  1024,  512,    0,    0, 0, 0);
    add(W_ri,  1024,  512,  512,    0, 0, 0);
    add(W_rv,  1024,  512, 1024,    0, 0, 0);
    add(W_rq,  1024,  512, 1536,    0, 0, 0);
    add(W_sw,  1024,  512, 2048,    0, 0, 0);
    add(W_sg,  1024,  512, 2560,    0, 0, 0);
    add(W_sd,  1024,  512, 3072,    0, 0, 0);
    add(W_sq,  1024,  512, 3584,    0, 0, 0);
    add(W_som, 1024,  256, 4096,    0, 0, 0);
    add(W_up,  1024, 1024, 4352,    0, 0, 1);   // interleaved: [up16|gate16] superblocks
    add(W_gate,1024, 1024, 4352,    0, 0, 2);
    add(W_ro,   512, 1024,    0,    0, 1, 0);
    add(W_so,   512, 1024,    0,  512, 1, 0);
    add(W_down,1024, 1024,    0, 1024, 1, 0);
    pack_w_kernel<<<dim3(32, 32, 14), 256, 0, stream>>>(ops, w1, w2);

    gemm1_proj<<<dim3(N1_ / 128, BT_ / 128), 256, 0, stream>>>(
        xb, w1, proj, swb, mw, G, BT_, N1_, K1_);

    scan_pass1<<<dim3(NCH_, B_, 3), 256, 0, stream>>>(proj, swb, rsP, rsY, ssM, ssY);
    scan_pass2<<<12, 256, 0, stream>>>(rsP, rsY, ssM, ssY, read_init, stable_init, rsStart, ssStart);
    scan_pass3<<<dim3(NCH_, B_, 3), 256, 0, stream>>>(proj, swb, rsStart, ssStart, mw, G);

    gemm2_f32<<<dim3(N2_ / 128, BT_ / 128), 256, 0, stream>>>(
        G, w2, (float*)d_out, BT_, N2_, K2_);
}